// Round 7
// baseline (491.468 us; speedup 1.0000x reference)
//
#include <hip/hip_runtime.h>
#include <stdint.h>

#define NN 8192
#define DD 128

typedef float f32x4 __attribute__((ext_vector_type(4)));
typedef short bf16x8 __attribute__((ext_vector_type(8)));

union B8 { uint32_t u[4]; bf16x8 v; };

__device__ inline uint16_t f2bf(float f) {
  uint32_t u = __builtin_bit_cast(uint32_t, f);
  uint32_t r = (u + 0x7FFFu + ((u >> 16) & 1u)) >> 16;
  return (uint16_t)r;
}

__device__ inline f32x4 mfma16(bf16x8 a, bf16x8 b, f32x4 c) {
  return __builtin_amdgcn_mfma_f32_16x16x32_bf16(a, b, c, 0, 0, 0);
}

// ---- K-A (fused): blocks 0..127 = prep (bf16 copies, x2, inits);
//                   blocks 128..639 = bitgen (sim -> bmT + counts4).
//      The two halves are data-independent (counts4 is written only by bitgen,
//      each slot exactly once -> no init needed, no race).
__global__ __launch_bounds__(256, 2) void k_prepbit(const float* __restrict__ inp,
                                                    const int* __restrict__ sim,
                                                    uint16_t* __restrict__ inp_bf,
                                                    uint16_t* __restrict__ inpT_bf,
                                                    float* __restrict__ x2p,
                                                    uint32_t* __restrict__ bmT,
                                                    uint32_t* __restrict__ counts4,
                                                    uint32_t* __restrict__ negkey,
                                                    uint32_t* __restrict__ tickets,
                                                    float* __restrict__ out) {
  __shared__ uint16_t ldsT[128 * 65];
  __shared__ float ldsS[256];
  __shared__ uint32_t ldsW[64 * 64];
  const int tid = threadIdx.x, lane = tid & 63, w = tid >> 6;

  if (blockIdx.x < 128) {
    // ---------------- prep ----------------
    const int px = blockIdx.x;
    const int gid = px * 256 + tid;
    if (gid < NN) negkey[gid] = 0xFFFFFFFFu;
    if (px == 0 && tid < 128) tickets[tid] = 0u;
    if (gid == 0) out[0] = 0.f;
    const int j0 = px * 64;
    const int r = tid >> 2;
    const int dseg = (tid & 3) * 32;
    float ss = 0.f;
#pragma unroll
    for (int it = 0; it < 8; ++it) {
      float4 v = *(const float4*)(inp + (size_t)(j0 + r) * DD + dseg + it * 4);
      ss += v.x * v.x + v.y * v.y + v.z * v.z + v.w * v.w;
      uint16_t b0 = f2bf(v.x), b1 = f2bf(v.y), b2 = f2bf(v.z), b3 = f2bf(v.w);
      *(ushort4*)(inp_bf + (size_t)(j0 + r) * DD + dseg + it * 4) = make_ushort4(b0, b1, b2, b3);
      int d = dseg + it * 4;
      ldsT[(d + 0) * 65 + r] = b0;
      ldsT[(d + 1) * 65 + r] = b1;
      ldsT[(d + 2) * 65 + r] = b2;
      ldsT[(d + 3) * 65 + r] = b3;
    }
    ldsS[tid] = ss;
    __syncthreads();
    if (tid < 64)
      x2p[j0 + tid] = ldsS[tid * 4] + ldsS[tid * 4 + 1] + ldsS[tid * 4 + 2] + ldsS[tid * 4 + 3] + 512.0f;
#pragma unroll
    for (int it = 0; it < 32; ++it) {
      int flat = it * 256 + tid;
      int d = flat >> 6, jl = flat & 63;
      inpT_bf[(size_t)d * NN + j0 + jl] = ldsT[d * 65 + jl];
    }
    return;
  }

  // ---------------- bitgen (2-deep row pipeline) ----------------
  const int bx = blockIdx.x - 128;
  const int m0 = (bx & 127) * 64;
  const int cy = bx >> 7;
  const int c0 = cy * 2048;
  int va[32], vb[32];
  {
    const int* p = sim + (size_t)(m0 + w) * NN + c0 + lane;
#pragma unroll
    for (int s = 0; s < 32; ++s) va[s] = p[s * 64];
  }
#pragma unroll 1
  for (int rr = 0; rr < 16; ++rr) {
    const int rl = rr * 4 + w;
    if (rr < 15) {
      const int* p = sim + (size_t)(m0 + rl + 4) * NN + c0 + lane;
#pragma unroll
      for (int s = 0; s < 32; ++s) vb[s] = p[s * 64];
    }
    uint32_t cnt = 0;
#pragma unroll
    for (int s = 0; s < 32; ++s) {
      unsigned long long ball = __ballot(va[s] != 0);
      cnt += (uint32_t)__popcll(ball);
      if ((lane & 31) == 0)
        ldsW[(s * 2 + (lane >> 5)) * 64 + rl] = (uint32_t)(ball >> (lane & 32));
    }
    if (lane == 0) counts4[(size_t)cy * NN + m0 + rl] = cnt;  // exactly-once plain store
#pragma unroll
    for (int s = 0; s < 32; ++s) va[s] = vb[s];
  }
  __syncthreads();
#pragma unroll
  for (int it = 0; it < 16; ++it) {
    int idx = it * 256 + tid;
    int kw = idx >> 6, r = idx & 63;
    bmT[(size_t)((c0 >> 5) + kw) * NN + m0 + r] = ldsW[idx];
  }
}

// ---- K-B: centers partials = mask @ inputs (bf16 MFMA), K-split 8, BK=64.
//      Last block per m-tile (device ticket) reduces partials -> centers (+bf16).
__global__ __launch_bounds__(256, 4) void k_gemm1(const uint16_t* __restrict__ inpT,
                                                  const uint32_t* __restrict__ bmT,
                                                  float* __restrict__ part,
                                                  const uint32_t* __restrict__ counts4,
                                                  uint32_t* __restrict__ tickets,
                                                  float* __restrict__ centers,
                                                  uint16_t* __restrict__ cen_bf) {
  __shared__ __align__(16) uint16_t ldsB[128 * 72];  // [dim][k0..63], pad to 72
  __shared__ uint32_t ldsM[128];                     // 64 rows x 2 kwords
  __shared__ int lastFlag;
  const int tid = threadIdx.x, lane = tid & 63, w = tid >> 6;
  const int col = lane & 15, quad = lane >> 4;
  const int m0 = blockIdx.x * 64;
  const int kb0 = blockIdx.y * 1024;
  const int wm = (w >> 1) * 32, wn = (w & 1) * 64;
  const int dim = tid >> 1, koff = (tid & 1) * 32;
  const int mrow = tid >> 1, msel = tid & 1;  // valid for tid<128
  f32x4 acc[2][4];
  const f32x4 z = {0.f, 0.f, 0.f, 0.f};
#pragma unroll
  for (int r = 0; r < 2; ++r)
#pragma unroll
    for (int c = 0; c < 4; ++c) acc[r][c] = z;

  bf16x8 bpf[4];
#pragma unroll
  for (int it = 0; it < 4; ++it)
    bpf[it] = *(const bf16x8*)(inpT + (size_t)dim * NN + kb0 + koff + it * 8);
  uint32_t mpf = (tid < 128) ? bmT[(size_t)((kb0 >> 5) + msel) * NN + m0 + mrow] : 0u;

  for (int ks = 0; ks < 16; ++ks) {
    const int kb = kb0 + ks * 64;
    __syncthreads();
#pragma unroll
    for (int it = 0; it < 4; ++it)
      *(bf16x8*)(ldsB + dim * 72 + koff + it * 8) = bpf[it];
    if (tid < 128) ldsM[mrow * 2 + msel] = mpf;
    __syncthreads();
    if (ks < 15) {
#pragma unroll
      for (int it = 0; it < 4; ++it)
        bpf[it] = *(const bf16x8*)(inpT + (size_t)dim * NN + kb + 64 + koff + it * 8);
      if (tid < 128) mpf = bmT[(size_t)(((kb + 64) >> 5) + msel) * NN + m0 + mrow];
    }
#pragma unroll
    for (int h = 0; h < 2; ++h) {
      B8 af[2];
#pragma unroll
      for (int rr = 0; rr < 2; ++rr) {
        uint32_t word = ldsM[(wm + rr * 16 + col) * 2 + h];
        uint32_t b = (word >> (quad * 8)) & 0xFFu;
        uint32_t s = b * 0x8001u;  // b | b<<15
#pragma unroll
        for (int p = 0; p < 4; ++p) {
          uint32_t t = (s >> (2 * p)) & 0x10001u;
          af[rr].u[p] = t * 0x3F80u;  // {bf16(bit), bf16(bit)} packed
        }
      }
#pragma unroll
      for (int cc = 0; cc < 4; ++cc) {
        bf16x8 bfr = *(const bf16x8*)(ldsB + (wn + cc * 16 + col) * 72 + h * 32 + quad * 8);
#pragma unroll
        for (int rr = 0; rr < 2; ++rr) acc[rr][cc] = mfma16(af[rr].v, bfr, acc[rr][cc]);
      }
    }
  }
  float* pp = part + (size_t)blockIdx.y * NN * DD;
#pragma unroll
  for (int rr = 0; rr < 2; ++rr)
#pragma unroll
    for (int cc = 0; cc < 4; ++cc)
#pragma unroll
      for (int g = 0; g < 4; ++g)
        pp[(size_t)(m0 + wm + rr * 16 + quad * 4 + g) * DD + wn + cc * 16 + col] = acc[rr][cc][g];

  // ---- last-arriver reduction for this m-tile (release/acquire via ticket) ----
  __syncthreads();
  if (tid == 0) {
    __threadfence();  // release: prior partial stores visible device-wide
    lastFlag = (atomicAdd(&tickets[blockIdx.x], 1u) == 7u) ? 1 : 0;
  }
  __syncthreads();
  if (!lastFlag) return;
  __threadfence();  // acquire: see all 8 slices' stores
  const int base = m0 * DD;
#pragma unroll 1
  for (int r8 = 0; r8 < 8; ++r8) {
    const int li = r8 * 1024 + tid * 4;
    const int fidx = base + li;
    const int row = m0 + (li >> 7);
    const float inv = 1.0f / (float)(counts4[row] + counts4[NN + row] +
                                     counts4[2 * NN + row] + counts4[3 * NN + row]);
    float4 v = *(const float4*)(part + fidx);
#pragma unroll
    for (int s = 1; s < 8; ++s) {
      float4 u = *(const float4*)(part + (size_t)s * NN * DD + fidx);
      v.x += u.x; v.y += u.y; v.z += u.z; v.w += u.w;
    }
    v.x *= inv; v.y *= inv; v.z *= inv; v.w *= inv;
    *(float4*)(centers + fidx) = v;
    *(ushort4*)(cen_bf + fidx) = make_ushort4(f2bf(v.x), f2bf(v.y), f2bf(v.z), f2bf(v.w));
  }
}

// ---- K-C: fused dist-GEMM + masked hard-negative argmin (packed u32 keys) ----
__global__ __launch_bounds__(256, 4) void k_argmin(const uint16_t* __restrict__ cen_bf,
                                                   const uint16_t* __restrict__ inp_bf,
                                                   const uint32_t* __restrict__ bmT,
                                                   const float* __restrict__ x2p,
                                                   uint32_t* __restrict__ negkey) {
  __shared__ __align__(16) uint16_t ldsB[64 * 136];
  __shared__ uint32_t ldsM[128];
  __shared__ float ldsX[64];
  __shared__ uint32_t ldsR[64];
  const int tid = threadIdx.x, lane = tid & 63, w = tid >> 6;
  const int col = lane & 15, quad = lane >> 4;
  const int i0 = blockIdx.x * 64;
  const int jbase = blockIdx.y * 1024;
  const int wi = (w >> 1) * 32, wj = (w & 1) * 32;
  bf16x8 af[2][4];
#pragma unroll
  for (int rr = 0; rr < 2; ++rr)
#pragma unroll
    for (int kk = 0; kk < 4; ++kk)
      af[rr][kk] = *(const bf16x8*)(cen_bf + (size_t)(i0 + wi + rr * 16 + col) * DD + kk * 32 + quad * 8);
  if (tid < 64) ldsR[tid] = 0xFFFFFFFFu;
  uint32_t best[2][4];
#pragma unroll
  for (int rr = 0; rr < 2; ++rr)
#pragma unroll
    for (int g = 0; g < 4; ++g) best[rr][g] = 0xFFFFFFFFu;

  const int jl = tid >> 2, doff = (tid & 3) * 32;
  bf16x8 bpf[4];
#pragma unroll
  for (int it = 0; it < 4; ++it)
    bpf[it] = *(const bf16x8*)(inp_bf + (size_t)(jbase + jl) * DD + doff + it * 8);
  uint32_t mpf = (tid < 128) ? bmT[(size_t)((jbase >> 5) + (tid >> 6)) * NN + i0 + (tid & 63)] : 0u;
  float xpf = (tid >= 128 && tid < 192) ? x2p[jbase + tid - 128] : 0.f;

  for (int js = 0; js < 16; ++js) {
    const int j0 = jbase + js * 64;
    __syncthreads();
#pragma unroll
    for (int it = 0; it < 4; ++it)
      *(bf16x8*)(ldsB + jl * 136 + doff + it * 8) = bpf[it];
    if (tid < 128) ldsM[tid] = mpf;
    else if (tid < 192) ldsX[tid - 128] = xpf;
    __syncthreads();
    if (js < 15) {
#pragma unroll
      for (int it = 0; it < 4; ++it)
        bpf[it] = *(const bf16x8*)(inp_bf + (size_t)(j0 + 64 + jl) * DD + doff + it * 8);
      if (tid < 128) mpf = bmT[(size_t)(((j0 + 64) >> 5) + (tid >> 6)) * NN + i0 + (tid & 63)];
      else if (tid < 192) xpf = x2p[j0 + 64 + tid - 128];
    }
    f32x4 acc[2][2];
    const f32x4 z = {0.f, 0.f, 0.f, 0.f};
    acc[0][0] = z; acc[0][1] = z; acc[1][0] = z; acc[1][1] = z;
#pragma unroll
    for (int kk = 0; kk < 4; ++kk) {
      bf16x8 b0 = *(const bf16x8*)(ldsB + (wj + col) * 136 + kk * 32 + quad * 8);
      bf16x8 b1 = *(const bf16x8*)(ldsB + (wj + 16 + col) * 136 + kk * 32 + quad * 8);
      acc[0][0] = mfma16(af[0][kk], b0, acc[0][0]);
      acc[0][1] = mfma16(af[0][kk], b1, acc[0][1]);
      acc[1][0] = mfma16(af[1][kk], b0, acc[1][0]);
      acc[1][1] = mfma16(af[1][kk], b1, acc[1][1]);
    }
    const uint32_t wsel = (w & 1) * 64;
    uint32_t words[2][4];
#pragma unroll
    for (int rr = 0; rr < 2; ++rr)
#pragma unroll
      for (int g = 0; g < 4; ++g) words[rr][g] = ldsM[wsel + wi + rr * 16 + quad * 4 + g];
#pragma unroll
    for (int cc = 0; cc < 2; ++cc) {
      const int jj = wj + cc * 16 + col;
      const float xq = ldsX[jj];                    // x2[j] + 512 -> v in [512,1024)
      const uint32_t jpre = (uint32_t)(j0 + jj);    // 13 bits
      const int sh = 31 - (cc * 16 + col);          // mask bit -> sign position
#pragma unroll
      for (int rr = 0; rr < 2; ++rr)
#pragma unroll
        for (int g = 0; g < 4; ++g) {
          float v = fmaf(-2.0f, acc[rr][cc][g], xq);
          uint32_t u = __builtin_bit_cast(uint32_t, v);
          uint32_t key = (u & 0xFFFFE000u) | jpre;
          key |= (words[rr][g] << sh) & 0x80000000u;
          best[rr][g] = min(best[rr][g], key);
        }
    }
  }
#pragma unroll
  for (int rr = 0; rr < 2; ++rr)
#pragma unroll
    for (int g = 0; g < 4; ++g) {
      uint32_t k = best[rr][g];
#pragma unroll
      for (int d = 1; d < 16; d <<= 1) {
        uint32_t o = (uint32_t)__shfl_xor((int)k, d);
        k = min(k, o);
      }
      if (col == 0) atomicMin(&ldsR[wi + rr * 16 + quad * 4 + g], k);
    }
  __syncthreads();
  if (tid < 64) atomicMin(&negkey[i0 + tid], ldsR[tid]);
}

// ---------------- K-D: triplet loss (exact fp32), wave-per-anchor ----------------
__global__ __launch_bounds__(256) void k_loss(const float* __restrict__ centers,
                                              const float* __restrict__ inp,
                                              const uint32_t* __restrict__ negkey,
                                              float* __restrict__ out) {
  __shared__ float lds[4];
  const int tid = threadIdx.x, lane = tid & 63, w = tid >> 6;
  float local = 0.f;
#pragma unroll 1
  for (int a = 0; a < 4; ++a) {
    int i = blockIdx.x * 16 + w * 4 + a;
    float2 c = *(const float2*)(centers + (size_t)i * DD + lane * 2);
    float2 x = *(const float2*)(inp + (size_t)i * DD + lane * 2);
    uint32_t ni = negkey[i] & (NN - 1);
    float2 gv = *(const float2*)(inp + (size_t)ni * DD + lane * 2);
    float e0 = c.x - x.x + 1e-6f, e1 = c.y - x.y + 1e-6f;
    float f0 = c.x - gv.x + 1e-6f, f1 = c.y - gv.y + 1e-6f;
    float dap = e0 * e0 + e1 * e1;
    float dan = f0 * f0 + f1 * f1;
#pragma unroll
    for (int d = 32; d; d >>= 1) {
      dap += __shfl_down(dap, d);
      dan += __shfl_down(dan, d);
    }
    if (lane == 0) local += fmaxf(sqrtf(dap) - sqrtf(dan) + 0.3f, 0.f);
  }
  if (lane == 0) lds[w] = local;
  __syncthreads();
  if (tid == 0) atomicAdd(out, (lds[0] + lds[1] + lds[2] + lds[3]) * (1.0f / 8192.0f));
}

extern "C" void kernel_launch(void* const* d_in, const int* in_sizes, int n_in,
                              void* d_out, int out_size, void* d_ws, size_t ws_size,
                              hipStream_t stream) {
  (void)in_sizes; (void)n_in; (void)out_size; (void)ws_size;
  const float* inp = (const float*)d_in[0];
  const int* sim = (const int*)d_in[1];
  float* out = (float*)d_out;
  char* ws = (char*)d_ws;

  uint32_t* bmT     = (uint32_t*)ws;                                   // 8 MB  [kword][row]
  float* part       = (float*)(ws + (8u << 20));                       // 32 MB (8 K-splits)
  float* centers    = (float*)(ws + (40u << 20));                      // 4 MB
  uint16_t* inp_bf  = (uint16_t*)(ws + (44u << 20));                   // 2 MB
  uint16_t* inpT_bf = (uint16_t*)(ws + (46u << 20));                   // 2 MB
  uint16_t* cen_bf  = (uint16_t*)(ws + (48u << 20));                   // 2 MB
  float* x2p        = (float*)(ws + (50u << 20));                      // 32 KB
  uint32_t* counts4 = (uint32_t*)(ws + (50u << 20) + 32768u);          // 128 KB
  uint32_t* negkey  = (uint32_t*)(ws + (50u << 20) + 163840u);         // 32 KB
  uint32_t* tickets = (uint32_t*)(ws + (50u << 20) + 196608u);         // 512 B

  k_prepbit<<<640, 256, 0, stream>>>(inp, sim, inp_bf, inpT_bf, x2p, bmT, counts4,
                                     negkey, tickets, out);
  k_gemm1<<<dim3(128, 8), 256, 0, stream>>>(inpT_bf, bmT, part, counts4, tickets,
                                            centers, cen_bf);
  k_argmin<<<dim3(128, 8), 256, 0, stream>>>(cen_bf, inp_bf, bmT, x2p, negkey);
  k_loss<<<512, 256, 0, stream>>>(centers, inp, negkey, out);
}

// Round 8
// 446.612 us; speedup vs baseline: 1.1004x; 1.1004x over previous
//
#include <hip/hip_runtime.h>
#include <stdint.h>

#define NN 8192
#define DD 128

typedef float f32x4 __attribute__((ext_vector_type(4)));
typedef short bf16x8 __attribute__((ext_vector_type(8)));

union B8 { uint32_t u[4]; bf16x8 v; };

__device__ inline uint16_t f2bf(float f) {
  uint32_t u = __builtin_bit_cast(uint32_t, f);
  uint32_t r = (u + 0x7FFFu + ((u >> 16) & 1u)) >> 16;
  return (uint16_t)r;
}

__device__ inline f32x4 mfma16(bf16x8 a, bf16x8 b, f32x4 c) {
  return __builtin_amdgcn_mfma_f32_16x16x32_bf16(a, b, c, 0, 0, 0);
}

// ---- K1: bf16 copies (row-major + transposed) + biased x2; init counts/negkey/out ----
__global__ __launch_bounds__(256) void k_prep(const float* __restrict__ inp,
                                              uint16_t* __restrict__ inp_bf,
                                              uint16_t* __restrict__ inpT_bf,
                                              float* __restrict__ x2p,
                                              uint32_t* __restrict__ counts,
                                              uint32_t* __restrict__ negkey,
                                              float* __restrict__ out) {
  __shared__ uint16_t ldsT[128 * 65];
  __shared__ float ldsS[256];
  const int tid = threadIdx.x;
  const int gid = blockIdx.x * 256 + tid;
  if (gid < NN) { counts[gid] = 0u; negkey[gid] = 0xFFFFFFFFu; }
  if (gid == 0) out[0] = 0.f;
  const int j0 = blockIdx.x * 64;
  const int r = tid >> 2;
  const int dseg = (tid & 3) * 32;
  float ss = 0.f;
#pragma unroll
  for (int it = 0; it < 8; ++it) {
    float4 v = *(const float4*)(inp + (size_t)(j0 + r) * DD + dseg + it * 4);
    ss += v.x * v.x + v.y * v.y + v.z * v.z + v.w * v.w;
    uint16_t b0 = f2bf(v.x), b1 = f2bf(v.y), b2 = f2bf(v.z), b3 = f2bf(v.w);
    *(ushort4*)(inp_bf + (size_t)(j0 + r) * DD + dseg + it * 4) = make_ushort4(b0, b1, b2, b3);
    int d = dseg + it * 4;
    ldsT[(d + 0) * 65 + r] = b0;
    ldsT[(d + 1) * 65 + r] = b1;
    ldsT[(d + 2) * 65 + r] = b2;
    ldsT[(d + 3) * 65 + r] = b3;
  }
  ldsS[tid] = ss;
  __syncthreads();
  if (tid < 64)
    x2p[j0 + tid] = ldsS[tid * 4] + ldsS[tid * 4 + 1] + ldsS[tid * 4 + 2] + ldsS[tid * 4 + 3] + 512.0f;
#pragma unroll
  for (int it = 0; it < 32; ++it) {
    int flat = it * 256 + tid;
    int d = flat >> 6, jl = flat & 63;
    inpT_bf[(size_t)d * NN + j0 + jl] = ldsT[d * 65 + jl];
  }
}

// ---- K2: sim -> column-major bitmask (bmT[kword][row]) + counts ----
//      2-deep software pipeline: next row's 32 loads issue before current consume.
__global__ __launch_bounds__(256, 2) void k_bitgen(const int* __restrict__ sim,
                                                   uint32_t* __restrict__ bmT,
                                                   uint32_t* __restrict__ counts) {
  __shared__ uint32_t ldsW[64 * 64];
  const int tid = threadIdx.x, lane = tid & 63, w = tid >> 6;
  const int m0 = blockIdx.x * 64;
  const int c0 = blockIdx.y * 2048;
  int va[32], vb[32];
  {
    const int* p = sim + (size_t)(m0 + w) * NN + c0 + lane;
#pragma unroll
    for (int s = 0; s < 32; ++s) va[s] = p[s * 64];
  }
#pragma unroll 1
  for (int rr = 0; rr < 16; ++rr) {
    const int rl = rr * 4 + w;
    if (rr < 15) {
      const int* p = sim + (size_t)(m0 + rl + 4) * NN + c0 + lane;
#pragma unroll
      for (int s = 0; s < 32; ++s) vb[s] = p[s * 64];
    }
    uint32_t cnt = 0;
#pragma unroll
    for (int s = 0; s < 32; ++s) {
      unsigned long long ball = __ballot(va[s] != 0);
      cnt += (uint32_t)__popcll(ball);
      if ((lane & 31) == 0)
        ldsW[(s * 2 + (lane >> 5)) * 64 + rl] = (uint32_t)(ball >> (lane & 32));
    }
    if (lane == 0) atomicAdd(&counts[m0 + rl], cnt);
#pragma unroll
    for (int s = 0; s < 32; ++s) va[s] = vb[s];
  }
  __syncthreads();
#pragma unroll
  for (int it = 0; it < 16; ++it) {
    int idx = it * 256 + tid;
    int kw = idx >> 6, r = idx & 63;
    bmT[(size_t)((c0 >> 5) + kw) * NN + m0 + r] = ldsW[idx];
  }
}

// ---- K3: centers partials = mask @ inputs (bf16 MFMA from bitmask), K-split 8, BK=64 ----
__global__ __launch_bounds__(256, 4) void k_gemm1(const uint16_t* __restrict__ inpT,
                                                  const uint32_t* __restrict__ bmT,
                                                  float* __restrict__ part) {
  __shared__ __align__(16) uint16_t ldsB[128 * 72];  // [dim][k0..63], pad to 72
  __shared__ uint32_t ldsM[128];                     // 64 rows x 2 kwords
  const int tid = threadIdx.x, lane = tid & 63, w = tid >> 6;
  const int col = lane & 15, quad = lane >> 4;
  const int m0 = blockIdx.x * 64;
  const int kb0 = blockIdx.y * 1024;
  const int wm = (w >> 1) * 32, wn = (w & 1) * 64;
  const int dim = tid >> 1, koff = (tid & 1) * 32;
  const int mrow = tid >> 1, msel = tid & 1;  // valid for tid<128
  f32x4 acc[2][4];
  const f32x4 z = {0.f, 0.f, 0.f, 0.f};
#pragma unroll
  for (int r = 0; r < 2; ++r)
#pragma unroll
    for (int c = 0; c < 4; ++c) acc[r][c] = z;

  bf16x8 bpf[4];
#pragma unroll
  for (int it = 0; it < 4; ++it)
    bpf[it] = *(const bf16x8*)(inpT + (size_t)dim * NN + kb0 + koff + it * 8);
  uint32_t mpf = (tid < 128) ? bmT[(size_t)((kb0 >> 5) + msel) * NN + m0 + mrow] : 0u;

  for (int ks = 0; ks < 16; ++ks) {
    const int kb = kb0 + ks * 64;
    __syncthreads();
#pragma unroll
    for (int it = 0; it < 4; ++it)
      *(bf16x8*)(ldsB + dim * 72 + koff + it * 8) = bpf[it];
    if (tid < 128) ldsM[mrow * 2 + msel] = mpf;
    __syncthreads();
    if (ks < 15) {
#pragma unroll
      for (int it = 0; it < 4; ++it)
        bpf[it] = *(const bf16x8*)(inpT + (size_t)dim * NN + kb + 64 + koff + it * 8);
      if (tid < 128) mpf = bmT[(size_t)(((kb + 64) >> 5) + msel) * NN + m0 + mrow];
    }
#pragma unroll
    for (int h = 0; h < 2; ++h) {
      B8 af[2];
#pragma unroll
      for (int rr = 0; rr < 2; ++rr) {
        uint32_t word = ldsM[(wm + rr * 16 + col) * 2 + h];
        uint32_t b = (word >> (quad * 8)) & 0xFFu;
        uint32_t s = b * 0x8001u;  // b | b<<15
#pragma unroll
        for (int p = 0; p < 4; ++p) {
          uint32_t t = (s >> (2 * p)) & 0x10001u;
          af[rr].u[p] = t * 0x3F80u;  // {bf16(bit), bf16(bit)} packed
        }
      }
#pragma unroll
      for (int cc = 0; cc < 4; ++cc) {
        bf16x8 bfr = *(const bf16x8*)(ldsB + (wn + cc * 16 + col) * 72 + h * 32 + quad * 8);
#pragma unroll
        for (int rr = 0; rr < 2; ++rr) acc[rr][cc] = mfma16(af[rr].v, bfr, acc[rr][cc]);
      }
    }
  }
  float* pp = part + (size_t)blockIdx.y * NN * DD;
#pragma unroll
  for (int rr = 0; rr < 2; ++rr)
#pragma unroll
    for (int cc = 0; cc < 4; ++cc)
#pragma unroll
      for (int g = 0; g < 4; ++g)
        pp[(size_t)(m0 + wm + rr * 16 + quad * 4 + g) * DD + wn + cc * 16 + col] = acc[rr][cc][g];
}

// ---- K4: reduce 8 partials, divide by counts, emit fp32 + bf16 centers ----
__global__ __launch_bounds__(256) void k_reduce(const float* __restrict__ part,
                                                const uint32_t* __restrict__ counts,
                                                float* __restrict__ centers,
                                                uint16_t* __restrict__ cen_bf) {
  const int gid = blockIdx.x * 256 + threadIdx.x;
  const int idx = gid * 4;
  const int row = idx >> 7;
  const float inv = 1.0f / (float)counts[row];
  float4 v = *(const float4*)(part + idx);
#pragma unroll
  for (int s = 1; s < 8; ++s) {
    float4 u = *(const float4*)(part + (size_t)s * NN * DD + idx);
    v.x += u.x; v.y += u.y; v.z += u.z; v.w += u.w;
  }
  v.x *= inv; v.y *= inv; v.z *= inv; v.w *= inv;
  *(float4*)(centers + idx) = v;
  *(ushort4*)(cen_bf + idx) = make_ushort4(f2bf(v.x), f2bf(v.y), f2bf(v.z), f2bf(v.w));
}

// ---- K5: fused dist-GEMM + masked hard-negative argmin (packed u32 keys) ----
__global__ __launch_bounds__(256, 4) void k_argmin(const uint16_t* __restrict__ cen_bf,
                                                   const uint16_t* __restrict__ inp_bf,
                                                   const uint32_t* __restrict__ bmT,
                                                   const float* __restrict__ x2p,
                                                   uint32_t* __restrict__ negkey) {
  __shared__ __align__(16) uint16_t ldsB[64 * 136];
  __shared__ uint32_t ldsM[128];
  __shared__ float ldsX[64];
  __shared__ uint32_t ldsR[64];
  const int tid = threadIdx.x, lane = tid & 63, w = tid >> 6;
  const int col = lane & 15, quad = lane >> 4;
  const int i0 = blockIdx.x * 64;
  const int jbase = blockIdx.y * 1024;
  const int wi = (w >> 1) * 32, wj = (w & 1) * 32;
  bf16x8 af[2][4];
#pragma unroll
  for (int rr = 0; rr < 2; ++rr)
#pragma unroll
    for (int kk = 0; kk < 4; ++kk)
      af[rr][kk] = *(const bf16x8*)(cen_bf + (size_t)(i0 + wi + rr * 16 + col) * DD + kk * 32 + quad * 8);
  if (tid < 64) ldsR[tid] = 0xFFFFFFFFu;
  uint32_t best[2][4];
#pragma unroll
  for (int rr = 0; rr < 2; ++rr)
#pragma unroll
    for (int g = 0; g < 4; ++g) best[rr][g] = 0xFFFFFFFFu;

  const int jl = tid >> 2, doff = (tid & 3) * 32;
  bf16x8 bpf[4];
#pragma unroll
  for (int it = 0; it < 4; ++it)
    bpf[it] = *(const bf16x8*)(inp_bf + (size_t)(jbase + jl) * DD + doff + it * 8);
  uint32_t mpf = (tid < 128) ? bmT[(size_t)((jbase >> 5) + (tid >> 6)) * NN + i0 + (tid & 63)] : 0u;
  float xpf = (tid >= 128 && tid < 192) ? x2p[jbase + tid - 128] : 0.f;

  for (int js = 0; js < 16; ++js) {
    const int j0 = jbase + js * 64;
    __syncthreads();
#pragma unroll
    for (int it = 0; it < 4; ++it)
      *(bf16x8*)(ldsB + jl * 136 + doff + it * 8) = bpf[it];
    if (tid < 128) ldsM[tid] = mpf;
    else if (tid < 192) ldsX[tid - 128] = xpf;
    __syncthreads();
    if (js < 15) {
#pragma unroll
      for (int it = 0; it < 4; ++it)
        bpf[it] = *(const bf16x8*)(inp_bf + (size_t)(j0 + 64 + jl) * DD + doff + it * 8);
      if (tid < 128) mpf = bmT[(size_t)(((j0 + 64) >> 5) + (tid >> 6)) * NN + i0 + (tid & 63)];
      else if (tid < 192) xpf = x2p[j0 + 64 + tid - 128];
    }
    f32x4 acc[2][2];
    const f32x4 z = {0.f, 0.f, 0.f, 0.f};
    acc[0][0] = z; acc[0][1] = z; acc[1][0] = z; acc[1][1] = z;
#pragma unroll
    for (int kk = 0; kk < 4; ++kk) {
      bf16x8 b0 = *(const bf16x8*)(ldsB + (wj + col) * 136 + kk * 32 + quad * 8);
      bf16x8 b1 = *(const bf16x8*)(ldsB + (wj + 16 + col) * 136 + kk * 32 + quad * 8);
      acc[0][0] = mfma16(af[0][kk], b0, acc[0][0]);
      acc[0][1] = mfma16(af[0][kk], b1, acc[0][1]);
      acc[1][0] = mfma16(af[1][kk], b0, acc[1][0]);
      acc[1][1] = mfma16(af[1][kk], b1, acc[1][1]);
    }
    const uint32_t wsel = (w & 1) * 64;
    uint32_t words[2][4];
#pragma unroll
    for (int rr = 0; rr < 2; ++rr)
#pragma unroll
      for (int g = 0; g < 4; ++g) words[rr][g] = ldsM[wsel + wi + rr * 16 + quad * 4 + g];
#pragma unroll
    for (int cc = 0; cc < 2; ++cc) {
      const int jj = wj + cc * 16 + col;
      const float xq = ldsX[jj];                    // x2[j] + 512 -> v in [512,1024)
      const uint32_t jpre = (uint32_t)(j0 + jj);    // 13 bits
      const int sh = 31 - (cc * 16 + col);          // mask bit -> sign position
#pragma unroll
      for (int rr = 0; rr < 2; ++rr)
#pragma unroll
        for (int g = 0; g < 4; ++g) {
          float v = fmaf(-2.0f, acc[rr][cc][g], xq);
          uint32_t u = __builtin_bit_cast(uint32_t, v);
          uint32_t key = (u & 0xFFFFE000u) | jpre;
          key |= (words[rr][g] << sh) & 0x80000000u;
          best[rr][g] = min(best[rr][g], key);
        }
    }
  }
#pragma unroll
  for (int rr = 0; rr < 2; ++rr)
#pragma unroll
    for (int g = 0; g < 4; ++g) {
      uint32_t k = best[rr][g];
#pragma unroll
      for (int d = 1; d < 16; d <<= 1) {
        uint32_t o = (uint32_t)__shfl_xor((int)k, d);
        k = min(k, o);
      }
      if (col == 0) atomicMin(&ldsR[wi + rr * 16 + quad * 4 + g], k);
    }
  __syncthreads();
  if (tid < 64) atomicMin(&negkey[i0 + tid], ldsR[tid]);
}

// ---------------- K6: triplet loss (exact fp32), wave-per-anchor ----------------
__global__ __launch_bounds__(256) void k_loss(const float* __restrict__ centers,
                                              const float* __restrict__ inp,
                                              const uint32_t* __restrict__ negkey,
                                              float* __restrict__ out) {
  __shared__ float lds[4];
  const int tid = threadIdx.x, lane = tid & 63, w = tid >> 6;
  float local = 0.f;
#pragma unroll 1
  for (int a = 0; a < 4; ++a) {
    int i = blockIdx.x * 16 + w * 4 + a;
    float2 c = *(const float2*)(centers + (size_t)i * DD + lane * 2);
    float2 x = *(const float2*)(inp + (size_t)i * DD + lane * 2);
    uint32_t ni = negkey[i] & (NN - 1);
    float2 gv = *(const float2*)(inp + (size_t)ni * DD + lane * 2);
    float e0 = c.x - x.x + 1e-6f, e1 = c.y - x.y + 1e-6f;
    float f0 = c.x - gv.x + 1e-6f, f1 = c.y - gv.y + 1e-6f;
    float dap = e0 * e0 + e1 * e1;
    float dan = f0 * f0 + f1 * f1;
#pragma unroll
    for (int d = 32; d; d >>= 1) {
      dap += __shfl_down(dap, d);
      dan += __shfl_down(dan, d);
    }
    if (lane == 0) local += fmaxf(sqrtf(dap) - sqrtf(dan) + 0.3f, 0.f);
  }
  if (lane == 0) lds[w] = local;
  __syncthreads();
  if (tid == 0) atomicAdd(out, (lds[0] + lds[1] + lds[2] + lds[3]) * (1.0f / 8192.0f));
}

extern "C" void kernel_launch(void* const* d_in, const int* in_sizes, int n_in,
                              void* d_out, int out_size, void* d_ws, size_t ws_size,
                              hipStream_t stream) {
  (void)in_sizes; (void)n_in; (void)out_size; (void)ws_size;
  const float* inp = (const float*)d_in[0];
  const int* sim = (const int*)d_in[1];
  float* out = (float*)d_out;
  char* ws = (char*)d_ws;

  uint32_t* bmT     = (uint32_t*)ws;                                   // 8 MB  [kword][row]
  float* part       = (float*)(ws + (8u << 20));                       // 32 MB (8 K-splits)
  float* centers    = (float*)(ws + (40u << 20));                      // 4 MB
  uint16_t* inp_bf  = (uint16_t*)(ws + (44u << 20));                   // 2 MB
  uint16_t* inpT_bf = (uint16_t*)(ws + (46u << 20));                   // 2 MB
  uint16_t* cen_bf  = (uint16_t*)(ws + (48u << 20));                   // 2 MB
  float* x2p        = (float*)(ws + (50u << 20));                      // 32 KB
  uint32_t* counts  = (uint32_t*)(ws + (50u << 20) + 32768u);          // 32 KB
  uint32_t* negkey  = (uint32_t*)(ws + (50u << 20) + 65536u);          // 32 KB

  k_prep<<<128, 256, 0, stream>>>(inp, inp_bf, inpT_bf, x2p, counts, negkey, out);
  k_bitgen<<<dim3(128, 4), 256, 0, stream>>>(sim, bmT, counts);
  k_gemm1<<<dim3(128, 8), 256, 0, stream>>>(inpT_bf, bmT, part);
  k_reduce<<<1024, 256, 0, stream>>>(part, counts, centers, cen_bf);
  k_argmin<<<dim3(128, 8), 256, 0, stream>>>(cen_bf, inp_bf, bmT, x2p, negkey);
  k_loss<<<512, 256, 0, stream>>>(centers, inp, negkey, out);
}